// Round 3
// baseline (577.895 us; speedup 1.0000x reference)
//
#include <hip/hip_runtime.h>

// GCN: h1 = relu(GCNConv(x,W1,b1)); h2 = relu(GCNConv(h1,W2,b2));
// g = max over nodes; out = log_softmax(g@fcW + fcb)
// GCNConv(v) = dinv[v]*( sum_{u->v} in[u]*dinv[u] + in[v]*dinv[v] )@W + b
//
// Round 3: no global CSR. Nodes are split into buckets of 128; edges are
// binned by dst-bucket as packed 4B words (src | dst_local<<17) with
// cacheline-granular writes (one block owns each line). Aggregation happens
// per bucket in LDS (f32 LDS atomics); the per-node W matvec + relu (+ max
// pool for layer 2) is fused into the same kernel. Layer 1 aggregates in the
// 8-dim input space (32 B/edge, xs table is L2-resident).
// Assumes N <= 131072 (17-bit src packing) and NBK <= 1024.

#define TPB 256
#define BSH 7                  // bucket = node >> 7  (128 nodes/bucket)
#define BN  128
#define BIN_CHUNK 12800        // edges per binning block (50 iters of 256)

// ---- binning ---------------------------------------------------------------

__global__ void k_bin(const int* __restrict__ src, const int* __restrict__ dst,
                      int* __restrict__ cursor, unsigned* __restrict__ binned,
                      int E, int NBK, int CAP) {
    __shared__ int hist[1024];
    __shared__ int base[1024];
    int t = threadIdx.x;
    int beg = blockIdx.x * BIN_CHUNK;
    int end = min(beg + BIN_CHUNK, E);
    for (int i = t; i < NBK; i += TPB) hist[i] = 0;
    __syncthreads();
    for (int i = beg + t; i < end; i += TPB)
        atomicAdd(&hist[dst[i] >> BSH], 1);
    __syncthreads();
    for (int b = t; b < NBK; b += TPB) {
        int c = hist[b];
        base[b] = c ? atomicAdd(&cursor[b], c) : 0;
        hist[b] = 0;
    }
    __syncthreads();
    for (int i = beg + t; i < end; i += TPB) {
        int d = dst[i];
        int b = d >> BSH;
        int r = atomicAdd(&hist[b], 1);
        int pos = base[b] + r;
        if (pos < CAP)
            binned[(size_t)b * CAP + pos] =
                (unsigned)src[i] | ((unsigned)(d & (BN - 1)) << 17);
    }
}

// ---- degrees -> dinv (block per bucket) ------------------------------------

__global__ void k_deg(const int* __restrict__ cursor, const unsigned* __restrict__ binned,
                      float* __restrict__ dinv, int N, int CAP) {
    __shared__ int h[BN];
    int t = threadIdx.x, b = blockIdx.x;
    if (t < BN) h[t] = 0;
    __syncthreads();
    int cnt = min(cursor[b], CAP);
    const unsigned* bp = binned + (size_t)b * CAP;
    for (int i = t; i < cnt; i += TPB) atomicAdd(&h[bp[i] >> 17], 1);
    __syncthreads();
    int v = (b << BSH) + t;
    if (t < BN && v < N) dinv[v] = rsqrtf((float)h[t] + 1.0f);
}

// ---- xs = x * dinv (pre-scaled layer-1 input, 8 floats/node) ---------------

__global__ void k_xs(const float* __restrict__ x, const float* __restrict__ dinv,
                     float* __restrict__ xs, int N) {
    int t = blockIdx.x * blockDim.x + threadIdx.x;
    if (t >= N * 2) return;
    int v = t >> 1;
    float4 a = ((const float4*)x)[t];
    float d = dinv[v];
    a.x *= d; a.y *= d; a.z *= d; a.w *= d;
    ((float4*)xs)[t] = a;
}

// ---- layer 1: aggregate xs (8-dim) per bucket, then W1 matvec+relu+prescale
__global__ void k_agg1(const float* __restrict__ xs, const unsigned* __restrict__ binned,
                       const int* __restrict__ cursor, const float* __restrict__ dinv,
                       const float* __restrict__ W1, const float* __restrict__ b1,
                       float* __restrict__ Hs1, int N, int CAP) {
    __shared__ float acc[BN * 9];      // stride 9: bank spread for atomics
    __shared__ float sW[8 * 32];
    int t = threadIdx.x, b = blockIdx.x;
    sW[t] = W1[t];                     // TPB == 256 == 8*32
    for (int i = t; i < BN * 9; i += TPB) acc[i] = 0.f;
    __syncthreads();
    int cnt = min(cursor[b], CAP);
    const unsigned* bp = binned + (size_t)b * CAP;
    for (int i = t; i < cnt; i += TPB) {
        unsigned w = bp[i];
        int s = w & 0x1FFFF, dl = w >> 17;
        const float4* xp = (const float4*)(xs + (size_t)s * 8);
        float4 a0 = xp[0], a1 = xp[1];
        float* ap = acc + dl * 9;
        atomicAdd(ap + 0, a0.x); atomicAdd(ap + 1, a0.y);
        atomicAdd(ap + 2, a0.z); atomicAdd(ap + 3, a0.w);
        atomicAdd(ap + 4, a1.x); atomicAdd(ap + 5, a1.y);
        atomicAdd(ap + 6, a1.z); atomicAdd(ap + 7, a1.w);
    }
    __syncthreads();
    int v0 = b << BSH;
    int nn = min(BN, N - v0);
    for (int i = t; i < nn * 8; i += TPB) {        // t8 = (acc + xs[v]) * dinv[v]
        int dl = i >> 3, f = i & 7;
        int v = v0 + dl;
        acc[dl * 9 + f] = (acc[dl * 9 + f] + xs[(size_t)v * 8 + f]) * dinv[v];
    }
    __syncthreads();
    float bb = b1[t & 31];                          // f == t&31 on every iter
    for (int i = t; i < nn * 32; i += TPB) {
        int dl = i >> 5, f = i & 31;
        int v = v0 + dl;
        float s = bb;
#pragma unroll
        for (int k = 0; k < 8; ++k) s = fmaf(acc[dl * 9 + k], sW[k * 32 + f], s);
        Hs1[(size_t)v * 32 + f] = fmaxf(s, 0.f) * dinv[v];
    }
}

// ---- layer 2: aggregate Hs1 (32-dim) per bucket, W2 matvec+relu, max pool --
__global__ void k_agg2(const float* __restrict__ Hs1, const unsigned* __restrict__ binned,
                       const int* __restrict__ cursor, const float* __restrict__ dinv,
                       const float* __restrict__ W2, const float* __restrict__ b2,
                       unsigned* __restrict__ gmax, int N, int CAP) {
    __shared__ float acc[BN * 33];     // stride 33: bank spread
    __shared__ float sW[32 * 32];
    __shared__ float red[TPB];
    int t = threadIdx.x, b = blockIdx.x;
    for (int i = t; i < 1024; i += TPB) sW[i] = W2[i];
    for (int i = t; i < BN * 33; i += TPB) acc[i] = 0.f;
    __syncthreads();
    int cnt = min(cursor[b], CAP);
    const unsigned* bp = binned + (size_t)b * CAP;
    for (int i = t; i < cnt; i += TPB) {
        unsigned w = bp[i];
        int s = w & 0x1FFFF, dl = w >> 17;
        const float4* hp = (const float4*)(Hs1 + (size_t)s * 32);
        float* ap = acc + dl * 33;
#pragma unroll
        for (int jj = 0; jj < 8; ++jj) {
            int q = (jj + t) & 7;                  // lane-rotated bank spread
            float4 v4 = hp[q];
            atomicAdd(ap + q * 4 + 0, v4.x); atomicAdd(ap + q * 4 + 1, v4.y);
            atomicAdd(ap + q * 4 + 2, v4.z); atomicAdd(ap + q * 4 + 3, v4.w);
        }
    }
    __syncthreads();
    int v0 = b << BSH;
    int nn = min(BN, N - v0);
    for (int i = t; i < nn * 32; i += TPB) {       // t = (acc + Hs1[v]) * dinv[v]
        int dl = i >> 5, k = i & 31;
        int v = v0 + dl;
        acc[dl * 33 + k] = (acc[dl * 33 + k] + Hs1[(size_t)v * 32 + k]) * dinv[v];
    }
    __syncthreads();
    float bb = b2[t & 31];
    float m = 0.f;                                  // relu floor folded into max
    for (int i = t; i < nn * 32; i += TPB) {
        int dl = i >> 5, f = i & 31;
        float s = bb;
#pragma unroll
        for (int k = 0; k < 32; ++k) s = fmaf(acc[dl * 33 + k], sW[k * 32 + f], s);
        m = fmaxf(m, s);
    }
    red[t] = m;
    __syncthreads();
    for (int off = 128; off >= 32; off >>= 1) {    // same f every 32 threads
        if (t < off) red[t] = fmaxf(red[t], red[t + off]);
        __syncthreads();
    }
    if (t < 32) atomicMax(&gmax[t], __float_as_uint(red[t]));
}

// ---- head ------------------------------------------------------------------

__global__ void k_head(const unsigned* __restrict__ gmax, const float* __restrict__ fcW,
                       const float* __restrict__ fcb, float* __restrict__ out) {
    if (threadIdx.x != 0 || blockIdx.x != 0) return;
    float g[32];
#pragma unroll
    for (int f = 0; f < 32; ++f) g[f] = __uint_as_float(gmax[f]);
    float logit[5];
    float mx = -1e30f;
#pragma unroll
    for (int c = 0; c < 5; ++c) {
        float s = fcb[c];
#pragma unroll
        for (int f = 0; f < 32; ++f) s += g[f] * fcW[f * 5 + c];
        logit[c] = s;
        mx = fmaxf(mx, s);
    }
    float lse = 0.f;
#pragma unroll
    for (int c = 0; c < 5; ++c) lse += expf(logit[c] - mx);
    lse = logf(lse) + mx;
#pragma unroll
    for (int c = 0; c < 5; ++c) out[c] = logit[c] - lse;
}

static inline size_t align256(size_t x) { return (x + 255) & ~size_t(255); }

extern "C" void kernel_launch(void* const* d_in, const int* in_sizes, int n_in,
                              void* d_out, int out_size, void* d_ws, size_t ws_size,
                              hipStream_t stream) {
    const float* x   = (const float*)d_in[0];
    const int*   ei  = (const int*)d_in[1];
    const float* W1  = (const float*)d_in[2];
    const float* b1  = (const float*)d_in[3];
    const float* W2  = (const float*)d_in[4];
    const float* b2  = (const float*)d_in[5];
    const float* fcW = (const float*)d_in[6];
    const float* fcb = (const float*)d_in[7];
    float* out = (float*)d_out;

    const int N = in_sizes[0] / 8;
    const int E = in_sizes[1] / 2;
    const int* src = ei;
    const int* dst = ei + E;

    const int NBK = (N + BN - 1) >> BSH;                  // 782 for N=100000
    const int avg = (E + NBK - 1) / NBK;                  // ~2047
    const int CAP = ((avg + (avg >> 2) + 64) + 15) & ~15; // 25% + slack, 64B-aligned

    char* ws = (char*)d_ws;
    size_t off = 0;
    int*      cursor = (int*)(ws + off);      off += align256((size_t)NBK * 4);
    float*    dinv   = (float*)(ws + off);    off += align256((size_t)N * 4);
    float*    xs     = (float*)(ws + off);    off += align256((size_t)N * 8 * 4);
    float*    Hs1    = (float*)(ws + off);    off += align256((size_t)N * 32 * 4);
    unsigned* gmax   = (unsigned*)(ws + off); off += align256(32 * 4);
    unsigned* binned = (unsigned*)(ws + off);

    dim3 blk(TPB);

    hipMemsetAsync(cursor, 0, (size_t)NBK * 4, stream);
    hipMemsetAsync(gmax, 0, 32 * 4, stream);

    k_bin<<<dim3((E + BIN_CHUNK - 1) / BIN_CHUNK), blk, 0, stream>>>(
        src, dst, cursor, binned, E, NBK, CAP);
    k_deg<<<dim3(NBK), blk, 0, stream>>>(cursor, binned, dinv, N, CAP);
    k_xs<<<dim3((N * 2 + TPB - 1) / TPB), blk, 0, stream>>>(x, dinv, xs, N);
    k_agg1<<<dim3(NBK), blk, 0, stream>>>(xs, binned, cursor, dinv, W1, b1, Hs1, N, CAP);
    k_agg2<<<dim3(NBK), blk, 0, stream>>>(Hs1, binned, cursor, dinv, W2, b2, gmax, N, CAP);
    k_head<<<dim3(1), dim3(64), 0, stream>>>(gmax, fcW, fcb, out);
}

// Round 4
// 279.426 us; speedup vs baseline: 2.0682x; 2.0682x over previous
//
#include <hip/hip_runtime.h>

// GCN: h1 = relu(GCNConv(x,W1,b1)); h2 = relu(GCNConv(h1,W2,b2));
// g = max over nodes; out = log_softmax(g@fcW + fcb)
// Per node: out[v] = dinv[v]*( Σ_{u->v} dinv[u]*h[u] + dinv[v]*h[v] )@W + b
//
// Round 4: R2's atomic-free gather engine + R3's cacheline-friendly binning
// as the CSR build. k_bin packs (src|dl<<17) bucket-major; k_reorder sorts
// each bucket in place by local dst (registers->LDS hist/scan->write back),
// producing per-node rowbeg/rowend into the SAME buffer. Layer-1 aggregates
// in 8-dim input space; W1+relu+W2 fused in one LDS kernel; layer-2 gather
// fused with global max pool. No float atomics, no scattered 4B stores.
// Assumes N <= 131072 (17-bit src packing), NBK <= 1024.

#define TPB 256
#define BSH 7                  // bucket = node >> 7  (128 nodes/bucket)
#define BN  128
#define BIN_CHUNK 12800        // edges per binning block

// ---- binning: pack edges bucket-major, cacheline-granular writes -----------

__global__ void k_bin(const int* __restrict__ src, const int* __restrict__ dst,
                      int* __restrict__ cursor, unsigned* __restrict__ binned,
                      int E, int NBK, int CAP) {
    __shared__ int hist[1024];
    __shared__ int base[1024];
    int t = threadIdx.x;
    int beg = blockIdx.x * BIN_CHUNK;
    int end = min(beg + BIN_CHUNK, E);
    for (int i = t; i < NBK; i += TPB) hist[i] = 0;
    __syncthreads();
    for (int i = beg + t; i < end; i += TPB)
        atomicAdd(&hist[dst[i] >> BSH], 1);
    __syncthreads();
    for (int b = t; b < NBK; b += TPB) {
        int c = hist[b];
        base[b] = c ? atomicAdd(&cursor[b], c) : 0;
        hist[b] = 0;
    }
    __syncthreads();
    for (int i = beg + t; i < end; i += TPB) {
        int d = dst[i];
        int b = d >> BSH;
        int r = atomicAdd(&hist[b], 1);
        int pos = base[b] + r;
        if (pos < CAP)
            binned[(size_t)b * CAP + pos] =
                (unsigned)src[i] | ((unsigned)(d & (BN - 1)) << 17);
    }
}

// ---- per-bucket: degree, dinv, rowbeg/rowend, in-place sort by local dst ---

__global__ void k_reorder(const int* __restrict__ cursor, unsigned* __restrict__ binned,
                          float* __restrict__ dinv, int* __restrict__ rowbeg,
                          int* __restrict__ rowend, int N, int CAP) {
    __shared__ int hist[BN];
    __shared__ int offs[BN];
    __shared__ int curs[BN];
    int t = threadIdx.x, b = blockIdx.x;
    int cnt = min(cursor[b], CAP);
    int gbase = b * CAP;
    unsigned ent[16];                    // ceil(CAP/TPB) <= 11
    int ne = 0;
    if (t < BN) hist[t] = 0;
    __syncthreads();
    for (int i = t; i < cnt; i += TPB) { // read ALL entries before any write
        unsigned w = binned[gbase + i];
        ent[ne++] = w;
        atomicAdd(&hist[w >> 17], 1);
    }
    __syncthreads();
    if (t < BN) offs[t] = hist[t];
    __syncthreads();
    for (int off = 1; off < BN; off <<= 1) {   // inclusive scan
        int v = 0;
        if (t >= off && t < BN) v = offs[t - off];
        __syncthreads();
        if (t < BN) offs[t] += v;
        __syncthreads();
    }
    if (t < BN) {
        int excl = offs[t] - hist[t];
        curs[t] = excl;
        int v = (b << BSH) + t;
        if (v < N) {
            dinv[v] = rsqrtf((float)hist[t] + 1.0f);
            rowbeg[v] = gbase + excl;
            rowend[v] = gbase + excl + hist[t];
        }
    }
    __syncthreads();
    for (int k = 0; k < ne; ++k) {       // write back node-sorted (src only)
        unsigned w = ent[k];
        int pos = atomicAdd(&curs[w >> 17], 1);
        binned[gbase + pos] = w & 0x1FFFF;
    }
}

// ---- xs = x * dinv ---------------------------------------------------------

__global__ void k_xs(const float* __restrict__ x, const float* __restrict__ dinv,
                     float* __restrict__ xs, int N) {
    int t = blockIdx.x * blockDim.x + threadIdx.x;
    if (t >= N * 2) return;
    int v = t >> 1;
    float4 a = ((const float4*)x)[t];
    float d = dinv[v];
    a.x *= d; a.y *= d; a.z *= d; a.w *= d;
    ((float4*)xs)[t] = a;
}

// ---- layer-1 aggregation in 8-dim space: agg8 = (Σ xs[u] + xs[v])*dinv[v] --

__global__ void k_gather8(const float* __restrict__ xs, const unsigned* __restrict__ adj,
                          const int* __restrict__ rowbeg, const int* __restrict__ rowend,
                          const float* __restrict__ dinv, float* __restrict__ agg8, int N) {
    int t = blockIdx.x * blockDim.x + threadIdx.x;
    if (t >= N * 2) return;
    int v = t >> 1, q = t & 1;
    int beg = rowbeg[v], end = rowend[v];
    float4 acc = ((const float4*)xs)[(size_t)v * 2 + q];   // self loop
    for (int j = beg; j < end; ++j) {
        int s = adj[j];
        float4 a = ((const float4*)xs)[(size_t)s * 2 + q];
        acc.x += a.x; acc.y += a.y; acc.z += a.z; acc.w += a.w;
    }
    float d = dinv[v];
    acc.x *= d; acc.y *= d; acc.z *= d; acc.w *= d;
    ((float4*)agg8)[(size_t)v * 2 + q] = acc;
}

// ---- fused dense: B = relu(agg8@W1 + b1)@W2 * dinv  (8 nodes / block) ------

__global__ void k_l12(const float* __restrict__ agg8, const float* __restrict__ W1,
                      const float* __restrict__ b1, const float* __restrict__ W2,
                      const float* __restrict__ dinv, float* __restrict__ B, int N) {
    __shared__ float sW1[8 * 32];
    __shared__ float sW2[32 * 32];
    __shared__ float sA[8 * 8];
    __shared__ float sH[8 * 32];
    int t = threadIdx.x;
    sW1[t] = W1[t];
#pragma unroll
    for (int i = t; i < 1024; i += TPB) sW2[i] = W2[i];
    int v0 = blockIdx.x * 8;
    if (t < 64) {
        int vv = v0 + (t >> 3);
        sA[t] = (vv < N) ? agg8[(size_t)v0 * 8 + t] : 0.f;
    }
    __syncthreads();
    int dl = t >> 5, f = t & 31;
    int v = v0 + dl;
    float s = b1[f];
#pragma unroll
    for (int k = 0; k < 8; ++k) s = fmaf(sA[dl * 8 + k], sW1[k * 32 + f], s);
    sH[dl * 32 + f] = fmaxf(s, 0.f);
    __syncthreads();
    if (v >= N) return;
    float s2 = 0.f;
#pragma unroll
    for (int k = 0; k < 32; ++k) s2 = fmaf(sH[dl * 32 + k], sW2[k * 32 + f], s2);
    B[(size_t)v * 32 + f] = s2 * dinv[v];
}

// ---- layer-2 gather + global max pool --------------------------------------
// out2[v] = dinv[v]*(Σ B[u] + B[v]) + b2; relu floor folded into 0-init max.
// Post-relu values >= 0 so uint-bit atomicMax with 0-init is exact float max.

__global__ void k_gather2max(const float* __restrict__ B, const unsigned* __restrict__ adj,
                             const int* __restrict__ rowbeg, const int* __restrict__ rowend,
                             const float* __restrict__ dinv, const float* __restrict__ b2,
                             unsigned* __restrict__ gmax, int N) {
    int tid = threadIdx.x;
    int q = tid & 7;
    float4 bb = ((const float4*)b2)[q];
    float4 m = make_float4(0.f, 0.f, 0.f, 0.f);
    int groups = (gridDim.x * blockDim.x) >> 3;
    for (int v = (blockIdx.x * blockDim.x + tid) >> 3; v < N; v += groups) {
        int beg = rowbeg[v], end = rowend[v];
        float4 acc = ((const float4*)B)[(size_t)v * 8 + q];   // self loop
        for (int j = beg; j < end; ++j) {
            int s = adj[j];
            float4 a = ((const float4*)B)[(size_t)s * 8 + q];
            acc.x += a.x; acc.y += a.y; acc.z += a.z; acc.w += a.w;
        }
        float d = dinv[v];
        m.x = fmaxf(m.x, fmaf(d, acc.x, bb.x));
        m.y = fmaxf(m.y, fmaf(d, acc.y, bb.y));
        m.z = fmaxf(m.z, fmaf(d, acc.z, bb.z));
        m.w = fmaxf(m.w, fmaf(d, acc.w, bb.w));
    }
    __shared__ float4 red[TPB];
    red[tid] = m;
    __syncthreads();
    for (int off = 128; off >= 8; off >>= 1) {
        if (tid < off) {
            float4 o = red[tid + off], c = red[tid];
            c.x = fmaxf(c.x, o.x); c.y = fmaxf(c.y, o.y);
            c.z = fmaxf(c.z, o.z); c.w = fmaxf(c.w, o.w);
            red[tid] = c;
        }
        __syncthreads();
    }
    if (tid < 8) {
        float4 r = red[tid];
        atomicMax(&gmax[tid * 4 + 0], __float_as_uint(r.x));
        atomicMax(&gmax[tid * 4 + 1], __float_as_uint(r.y));
        atomicMax(&gmax[tid * 4 + 2], __float_as_uint(r.z));
        atomicMax(&gmax[tid * 4 + 3], __float_as_uint(r.w));
    }
}

// ---- head ------------------------------------------------------------------

__global__ void k_head(const unsigned* __restrict__ gmax, const float* __restrict__ fcW,
                       const float* __restrict__ fcb, float* __restrict__ out) {
    if (threadIdx.x != 0 || blockIdx.x != 0) return;
    float g[32];
#pragma unroll
    for (int f = 0; f < 32; ++f) g[f] = __uint_as_float(gmax[f]);
    float logit[5];
    float mx = -1e30f;
#pragma unroll
    for (int c = 0; c < 5; ++c) {
        float s = fcb[c];
#pragma unroll
        for (int f = 0; f < 32; ++f) s += g[f] * fcW[f * 5 + c];
        logit[c] = s;
        mx = fmaxf(mx, s);
    }
    float lse = 0.f;
#pragma unroll
    for (int c = 0; c < 5; ++c) lse += expf(logit[c] - mx);
    lse = logf(lse) + mx;
#pragma unroll
    for (int c = 0; c < 5; ++c) out[c] = logit[c] - lse;
}

static inline size_t align256(size_t x) { return (x + 255) & ~size_t(255); }

extern "C" void kernel_launch(void* const* d_in, const int* in_sizes, int n_in,
                              void* d_out, int out_size, void* d_ws, size_t ws_size,
                              hipStream_t stream) {
    const float* x   = (const float*)d_in[0];
    const int*   ei  = (const int*)d_in[1];
    const float* W1  = (const float*)d_in[2];
    const float* b1  = (const float*)d_in[3];
    const float* W2  = (const float*)d_in[4];
    const float* b2  = (const float*)d_in[5];
    const float* fcW = (const float*)d_in[6];
    const float* fcb = (const float*)d_in[7];
    float* out = (float*)d_out;

    const int N = in_sizes[0] / 8;
    const int E = in_sizes[1] / 2;
    const int* src = ei;
    const int* dst = ei + E;

    const int NBK = (N + BN - 1) >> BSH;                  // 782 for N=100000
    const int avg = (E + NBK - 1) / NBK;                  // ~2047
    const int CAP = ((avg + (avg >> 2) + 64) + 15) & ~15; // mean +25% +slack

    char* ws = (char*)d_ws;
    size_t off = 0;
    int*      cursor = (int*)(ws + off);      off += align256((size_t)NBK * 4);
    float*    dinv   = (float*)(ws + off);    off += align256((size_t)N * 4);
    int*      rowbeg = (int*)(ws + off);      off += align256((size_t)N * 4);
    int*      rowend = (int*)(ws + off);      off += align256((size_t)N * 4);
    float*    xs     = (float*)(ws + off);    off += align256((size_t)N * 8 * 4);
    float*    agg8   = (float*)(ws + off);    off += align256((size_t)N * 8 * 4);
    float*    B      = (float*)(ws + off);    off += align256((size_t)N * 32 * 4);
    unsigned* gmax   = (unsigned*)(ws + off); off += align256(32 * 4);
    unsigned* binned = (unsigned*)(ws + off);

    dim3 blk(TPB);

    hipMemsetAsync(cursor, 0, (size_t)NBK * 4, stream);
    hipMemsetAsync(gmax, 0, 32 * 4, stream);

    k_bin<<<dim3((E + BIN_CHUNK - 1) / BIN_CHUNK), blk, 0, stream>>>(
        src, dst, cursor, binned, E, NBK, CAP);
    k_reorder<<<dim3(NBK), blk, 0, stream>>>(cursor, binned, dinv, rowbeg, rowend, N, CAP);
    k_xs<<<dim3((N * 2 + TPB - 1) / TPB), blk, 0, stream>>>(x, dinv, xs, N);
    k_gather8<<<dim3((N * 2 + TPB - 1) / TPB), blk, 0, stream>>>(
        xs, binned, rowbeg, rowend, dinv, agg8, N);
    k_l12<<<dim3((N + 7) / 8), blk, 0, stream>>>(agg8, W1, b1, W2, dinv, B, N);
    k_gather2max<<<dim3(1024), blk, 0, stream>>>(B, binned, rowbeg, rowend, dinv, b2, gmax, N);
    k_head<<<dim3(1), dim3(64), 0, stream>>>(gmax, fcW, fcb, out);
}

// Round 5
// 243.339 us; speedup vs baseline: 2.3749x; 1.1483x over previous
//
#include <hip/hip_runtime.h>

// GCN: h1 = relu(GCNConv(x,W1,b1)); h2 = relu(GCNConv(h1,W2,b2));
// g = max over nodes; out = log_softmax(g@fcW + fcb)
// Per node: out[v] = dinv[v]*( Σ_{u->v} dinv[u]*h[u] + dinv[v]*h[v] )@W + b
//
// Round 5: R4 structure + memory-level parallelism for the latency-bound
// gathers. Layer-2 gather: 16 threads/node (edge range split in half per
// 8-lane group, shfl_xor(8) combine), 4-way unrolled loads, 2048-block
// grid-stride, per-block partial maxes (no global atomics; k_head reduces).
// Layer-1 gather: 4 threads/node + shfl_xor(2), 4-way unroll. xs fused into
// k_reorder. Assumes N <= 131072 (17-bit packing), NBK <= 1024.

#define TPB 256
#define BSH 7                  // bucket = node >> 7  (128 nodes/bucket)
#define BN  128
#define BIN_CHUNK 12800        // edges per binning block
#define G2_BLOCKS 2048

static __device__ __forceinline__ float4 f4add(float4 a, float4 b) {
    return make_float4(a.x + b.x, a.y + b.y, a.z + b.z, a.w + b.w);
}
static __device__ __forceinline__ float4 f4max(float4 a, float4 b) {
    return make_float4(fmaxf(a.x, b.x), fmaxf(a.y, b.y),
                       fmaxf(a.z, b.z), fmaxf(a.w, b.w));
}

// ---- binning: pack edges bucket-major, cacheline-granular writes -----------

__global__ void k_bin(const int* __restrict__ src, const int* __restrict__ dst,
                      int* __restrict__ cursor, unsigned* __restrict__ binned,
                      int E, int NBK, int CAP) {
    __shared__ int hist[1024];
    __shared__ int base[1024];
    int t = threadIdx.x;
    int beg = blockIdx.x * BIN_CHUNK;
    int end = min(beg + BIN_CHUNK, E);
    for (int i = t; i < NBK; i += TPB) hist[i] = 0;
    __syncthreads();
    for (int i = beg + t; i < end; i += TPB)
        atomicAdd(&hist[dst[i] >> BSH], 1);
    __syncthreads();
    for (int b = t; b < NBK; b += TPB) {
        int c = hist[b];
        base[b] = c ? atomicAdd(&cursor[b], c) : 0;
        hist[b] = 0;
    }
    __syncthreads();
    for (int i = beg + t; i < end; i += TPB) {
        int d = dst[i];
        int b = d >> BSH;
        int r = atomicAdd(&hist[b], 1);
        int pos = base[b] + r;
        if (pos < CAP)
            binned[(size_t)b * CAP + pos] =
                (unsigned)src[i] | ((unsigned)(d & (BN - 1)) << 17);
    }
}

// ---- per bucket: degree, dinv, rowbeg/rowend, in-place sort, xs = x*dinv ---

__global__ void k_reorder(const int* __restrict__ cursor, unsigned* __restrict__ binned,
                          const float* __restrict__ x, float* __restrict__ dinv,
                          int* __restrict__ rowbeg, int* __restrict__ rowend,
                          float* __restrict__ xs, int N, int CAP) {
    __shared__ int hist[BN];
    __shared__ int offs[BN];
    __shared__ int curs[BN];
    __shared__ float sdv[BN];
    int t = threadIdx.x, b = blockIdx.x;
    int cnt = min(cursor[b], CAP);
    int gbase = b * CAP;
    unsigned ent[16];                    // ceil(CAP/TPB) <= 11
    int ne = 0;
    if (t < BN) hist[t] = 0;
    __syncthreads();
    for (int i = t; i < cnt; i += TPB) { // read ALL entries before any write
        unsigned w = binned[gbase + i];
        ent[ne++] = w;
        atomicAdd(&hist[w >> 17], 1);
    }
    __syncthreads();
    if (t < BN) offs[t] = hist[t];
    __syncthreads();
    for (int off = 1; off < BN; off <<= 1) {   // inclusive scan
        int v = 0;
        if (t >= off && t < BN) v = offs[t - off];
        __syncthreads();
        if (t < BN) offs[t] += v;
        __syncthreads();
    }
    if (t < BN) {
        int excl = offs[t] - hist[t];
        curs[t] = excl;
        float dv = rsqrtf((float)hist[t] + 1.0f);
        sdv[t] = dv;
        int v = (b << BSH) + t;
        if (v < N) {
            dinv[v] = dv;
            rowbeg[v] = gbase + excl;
            rowend[v] = gbase + excl + hist[t];
        }
    }
    __syncthreads();
    // xs: 128 nodes * 2 float4 = 256 float4s, one per thread (coalesced)
    {
        int vv = (b << BSH) + (t >> 1);
        if (vv < N) {
            float4 a = ((const float4*)x)[(size_t)vv * 2 + (t & 1)];
            float d = sdv[t >> 1];
            a.x *= d; a.y *= d; a.z *= d; a.w *= d;
            ((float4*)xs)[(size_t)vv * 2 + (t & 1)] = a;
        }
    }
    for (int k = 0; k < ne; ++k) {       // write back node-sorted (src only)
        unsigned w = ent[k];
        int pos = atomicAdd(&curs[w >> 17], 1);
        binned[gbase + pos] = w & 0x1FFFF;
    }
}

// ---- layer-1 aggregation (8-dim): agg8 = (Σ xs[u] + xs[v])*dinv[v] ---------
// 4 threads/node: q = float4 index, half = edge-range half; shfl_xor(2) join.

__global__ void k_gather8(const float* __restrict__ xs, const unsigned* __restrict__ adj,
                          const int* __restrict__ rowbeg, const int* __restrict__ rowend,
                          const float* __restrict__ dinv, float* __restrict__ agg8, int N) {
    int t = blockIdx.x * blockDim.x + threadIdx.x;
    if (t >= N * 4) return;
    int v = t >> 2, q = t & 1, half = (t >> 1) & 1;
    int beg = rowbeg[v], end = rowend[v];
    int h = (end - beg) >> 1;
    int b0 = half ? beg + h : beg;
    int e0 = half ? end : beg + h;
    const float4* X = (const float4*)xs;
    float4 A0 = make_float4(0, 0, 0, 0), A1 = A0, A2 = A0, A3 = A0;
    int j = b0;
    for (; j + 4 <= e0; j += 4) {
        int s0 = adj[j], s1 = adj[j + 1], s2 = adj[j + 2], s3 = adj[j + 3];
        A0 = f4add(A0, X[(size_t)s0 * 2 + q]);
        A1 = f4add(A1, X[(size_t)s1 * 2 + q]);
        A2 = f4add(A2, X[(size_t)s2 * 2 + q]);
        A3 = f4add(A3, X[(size_t)s3 * 2 + q]);
    }
    for (; j < e0; ++j) A0 = f4add(A0, X[(size_t)adj[j] * 2 + q]);
    float4 acc = f4add(f4add(A0, A1), f4add(A2, A3));
    if (!half) acc = f4add(acc, X[(size_t)v * 2 + q]);   // self loop
    acc.x += __shfl_xor(acc.x, 2);
    acc.y += __shfl_xor(acc.y, 2);
    acc.z += __shfl_xor(acc.z, 2);
    acc.w += __shfl_xor(acc.w, 2);
    if (!half) {
        float d = dinv[v];
        acc.x *= d; acc.y *= d; acc.z *= d; acc.w *= d;
        ((float4*)agg8)[(size_t)v * 2 + q] = acc;
    }
}

// ---- fused dense: B = relu(agg8@W1 + b1)@W2 * dinv  (8 nodes / block) ------

__global__ void k_l12(const float* __restrict__ agg8, const float* __restrict__ W1,
                      const float* __restrict__ b1, const float* __restrict__ W2,
                      const float* __restrict__ dinv, float* __restrict__ B, int N) {
    __shared__ float sW1[8 * 32];
    __shared__ float sW2[32 * 32];
    __shared__ float sA[8 * 8];
    __shared__ float sH[8 * 32];
    int t = threadIdx.x;
    sW1[t] = W1[t];
#pragma unroll
    for (int i = t; i < 1024; i += TPB) sW2[i] = W2[i];
    int v0 = blockIdx.x * 8;
    if (t < 64) {
        int vv = v0 + (t >> 3);
        sA[t] = (vv < N) ? agg8[(size_t)v0 * 8 + t] : 0.f;
    }
    __syncthreads();
    int dl = t >> 5, f = t & 31;
    int v = v0 + dl;
    float s = b1[f];
#pragma unroll
    for (int k = 0; k < 8; ++k) s = fmaf(sA[dl * 8 + k], sW1[k * 32 + f], s);
    sH[dl * 32 + f] = fmaxf(s, 0.f);
    __syncthreads();
    if (v >= N) return;
    float s2 = 0.f;
#pragma unroll
    for (int k = 0; k < 32; ++k) s2 = fmaf(sH[dl * 32 + k], sW2[k * 32 + f], s2);
    B[(size_t)v * 32 + f] = s2 * dinv[v];
}

// ---- layer-2 gather + per-block partial max pool ---------------------------
// 16 threads/node (8-lane half-ranges, shfl_xor(8) join); grid-stride.
// Partial max init 0 == relu floor; block writes its 32-float row (no atomics).

__global__ void k_gather32(const float* __restrict__ B, const unsigned* __restrict__ adj,
                           const int* __restrict__ rowbeg, const int* __restrict__ rowend,
                           const float* __restrict__ dinv, const float* __restrict__ b2,
                           float* __restrict__ partial, int N) {
    int tid = threadIdx.x;
    int sub = tid & 15, q = sub & 7, half = sub >> 3;
    float4 bb = ((const float4*)b2)[q];
    float4 m = make_float4(0.f, 0.f, 0.f, 0.f);
    const float4* Bp = (const float4*)B;
    int gstride = (gridDim.x * blockDim.x) >> 4;
    for (int v = (blockIdx.x * blockDim.x + tid) >> 4; v < N; v += gstride) {
        int beg = rowbeg[v], end = rowend[v];
        int h = (end - beg) >> 1;
        int b0 = half ? beg + h : beg;
        int e0 = half ? end : beg + h;
        float4 A0 = make_float4(0, 0, 0, 0), A1 = A0, A2 = A0, A3 = A0;
        int j = b0;
        for (; j + 4 <= e0; j += 4) {
            int s0 = adj[j], s1 = adj[j + 1], s2 = adj[j + 2], s3 = adj[j + 3];
            A0 = f4add(A0, Bp[(size_t)s0 * 8 + q]);
            A1 = f4add(A1, Bp[(size_t)s1 * 8 + q]);
            A2 = f4add(A2, Bp[(size_t)s2 * 8 + q]);
            A3 = f4add(A3, Bp[(size_t)s3 * 8 + q]);
        }
        for (; j < e0; ++j) A0 = f4add(A0, Bp[(size_t)adj[j] * 8 + q]);
        float4 acc = f4add(f4add(A0, A1), f4add(A2, A3));
        if (!half) acc = f4add(acc, Bp[(size_t)v * 8 + q]);   // self loop
        acc.x += __shfl_xor(acc.x, 8);
        acc.y += __shfl_xor(acc.y, 8);
        acc.z += __shfl_xor(acc.z, 8);
        acc.w += __shfl_xor(acc.w, 8);
        float d = dinv[v];
        m.x = fmaxf(m.x, fmaf(d, acc.x, bb.x));
        m.y = fmaxf(m.y, fmaf(d, acc.y, bb.y));
        m.z = fmaxf(m.z, fmaf(d, acc.z, bb.z));
        m.w = fmaxf(m.w, fmaf(d, acc.w, bb.w));
    }
    __shared__ float4 red[TPB];
    red[tid] = m;
    __syncthreads();
    for (int off = 128; off >= 16; off >>= 1) {   // off multiple of 8 keeps q
        if (tid < off) red[tid] = f4max(red[tid], red[tid + off]);
        __syncthreads();
    }
    if (tid < 8) {
        float4 r = f4max(red[tid], red[tid + 8]);
        ((float4*)(partial + (size_t)blockIdx.x * 32))[tid] = r;
    }
}

// ---- head: reduce partials, fc, log_softmax --------------------------------

__global__ void k_head(const float* __restrict__ partial, int npart,
                       const float* __restrict__ fcW, const float* __restrict__ fcb,
                       float* __restrict__ out) {
    __shared__ float red[TPB];
    int t = threadIdx.x;
    int f = t & 31, r0 = t >> 5;
    float m = 0.f;
    for (int r = r0; r < npart; r += 8) m = fmaxf(m, partial[(size_t)r * 32 + f]);
    red[t] = m;
    __syncthreads();
    for (int off = 128; off >= 32; off >>= 1) {
        if (t < off) red[t] = fmaxf(red[t], red[t + off]);
        __syncthreads();
    }
    if (t != 0) return;
    float logit[5];
    float mx = -1e30f;
#pragma unroll
    for (int c = 0; c < 5; ++c) {
        float s = fcb[c];
#pragma unroll
        for (int ff = 0; ff < 32; ++ff) s += red[ff] * fcW[ff * 5 + c];
        logit[c] = s;
        mx = fmaxf(mx, s);
    }
    float lse = 0.f;
#pragma unroll
    for (int c = 0; c < 5; ++c) lse += expf(logit[c] - mx);
    lse = logf(lse) + mx;
#pragma unroll
    for (int c = 0; c < 5; ++c) out[c] = logit[c] - lse;
}

static inline size_t align256(size_t x) { return (x + 255) & ~size_t(255); }

extern "C" void kernel_launch(void* const* d_in, const int* in_sizes, int n_in,
                              void* d_out, int out_size, void* d_ws, size_t ws_size,
                              hipStream_t stream) {
    const float* x   = (const float*)d_in[0];
    const int*   ei  = (const int*)d_in[1];
    const float* W1  = (const float*)d_in[2];
    const float* b1  = (const float*)d_in[3];
    const float* W2  = (const float*)d_in[4];
    const float* b2  = (const float*)d_in[5];
    const float* fcW = (const float*)d_in[6];
    const float* fcb = (const float*)d_in[7];
    float* out = (float*)d_out;

    const int N = in_sizes[0] / 8;
    const int E = in_sizes[1] / 2;
    const int* src = ei;
    const int* dst = ei + E;

    const int NBK = (N + BN - 1) >> BSH;                  // 782 for N=100000
    const int avg = (E + NBK - 1) / NBK;                  // ~2047
    const int CAP = ((avg + (avg >> 2) + 64) + 15) & ~15; // mean +25% +slack

    char* ws = (char*)d_ws;
    size_t off = 0;
    int*      cursor  = (int*)(ws + off);   off += align256((size_t)NBK * 4);
    float*    dinv    = (float*)(ws + off); off += align256((size_t)N * 4);
    int*      rowbeg  = (int*)(ws + off);   off += align256((size_t)N * 4);
    int*      rowend  = (int*)(ws + off);   off += align256((size_t)N * 4);
    float*    xs      = (float*)(ws + off); off += align256((size_t)N * 8 * 4);
    float*    agg8    = (float*)(ws + off); off += align256((size_t)N * 8 * 4);
    float*    B       = (float*)(ws + off); off += align256((size_t)N * 32 * 4);
    float*    partial = (float*)(ws + off); off += align256((size_t)G2_BLOCKS * 32 * 4);
    unsigned* binned  = (unsigned*)(ws + off);

    dim3 blk(TPB);

    hipMemsetAsync(cursor, 0, (size_t)NBK * 4, stream);

    k_bin<<<dim3((E + BIN_CHUNK - 1) / BIN_CHUNK), blk, 0, stream>>>(
        src, dst, cursor, binned, E, NBK, CAP);
    k_reorder<<<dim3(NBK), blk, 0, stream>>>(cursor, binned, x, dinv, rowbeg, rowend,
                                             xs, N, CAP);
    k_gather8<<<dim3((N * 4 + TPB - 1) / TPB), blk, 0, stream>>>(
        xs, binned, rowbeg, rowend, dinv, agg8, N);
    k_l12<<<dim3((N + 7) / 8), blk, 0, stream>>>(agg8, W1, b1, W2, dinv, B, N);
    k_gather32<<<dim3(G2_BLOCKS), blk, 0, stream>>>(B, binned, rowbeg, rowend,
                                                    dinv, b2, partial, N);
    k_head<<<dim3(1), blk, 0, stream>>>(partial, G2_BLOCKS, fcW, fcb, out);
}

// Round 6
// 204.986 us; speedup vs baseline: 2.8192x; 1.1871x over previous
//
#include <hip/hip_runtime.h>
#include <hip/hip_fp16.h>

// GCN: h1 = relu(GCNConv(x,W1,b1)); h2 = relu(GCNConv(h1,W2,b2));
// g = max over nodes; out = log_softmax(g@fcW + fcb)
// Per node: out[v] = dinv[v]*( Σ_{u->v} dinv[u]*h[u] + dinv[v]*h[v] )@W + b
//
// Round 6: (1) k_bin at TPB=1024 with register-cached packed words — 4x waves
// at identical atomic contention; (2) fp16 feature tables (xs: 16 B/row,
// B: 64 B/row) with fp32 accumulation — halves gather traffic; gather32 uses
// 16 lanes/node (4 quarter-ranges x 4 chunks) for MLP.
// Assumes N <= 131072 (17-bit packing), NBK <= 1024.

#define TPB 256
#define TPB_BIN 1024
#define BSH 7                  // bucket = node >> 7  (128 nodes/bucket)
#define BN  128
#define BIN_CHUNK 12800        // edges per binning block
#define G2_BLOCKS 2048

static __device__ __forceinline__ void acc8(float a[8], uint4 u) {
    float2 f0 = __half22float2(*(__half2*)&u.x);
    float2 f1 = __half22float2(*(__half2*)&u.y);
    float2 f2 = __half22float2(*(__half2*)&u.z);
    float2 f3 = __half22float2(*(__half2*)&u.w);
    a[0] += f0.x; a[1] += f0.y; a[2] += f1.x; a[3] += f1.y;
    a[4] += f2.x; a[5] += f2.y; a[6] += f3.x; a[7] += f3.y;
}

// ---- binning: pack edges bucket-major, cacheline-granular writes -----------

__global__ __launch_bounds__(TPB_BIN) void
k_bin(const int* __restrict__ src, const int* __restrict__ dst,
      int* __restrict__ cursor, unsigned* __restrict__ binned,
      int E, int NBK, int CAP) {
    __shared__ int hist[1024];
    __shared__ int base[1024];
    int t = threadIdx.x;
    int beg = blockIdx.x * BIN_CHUNK;
    int end = min(beg + BIN_CHUNK, E);
    for (int i = t; i < NBK; i += TPB_BIN) hist[i] = 0;
    __syncthreads();
    unsigned wc[13];
    int      bc[13];
    int ne = 0;
    for (int i = beg + t; i < end; i += TPB_BIN) {
        int d = dst[i], s = src[i];
        int b = d >> BSH;
        wc[ne] = (unsigned)s | ((unsigned)(d & (BN - 1)) << 17);
        bc[ne] = b;
        ne++;
        atomicAdd(&hist[b], 1);
    }
    __syncthreads();
    for (int b = t; b < NBK; b += TPB_BIN) {
        int c = hist[b];
        base[b] = c ? atomicAdd(&cursor[b], c) : 0;
        hist[b] = 0;
    }
    __syncthreads();
    for (int k = 0; k < ne; ++k) {
        int b = bc[k];
        int r = atomicAdd(&hist[b], 1);
        int pos = base[b] + r;
        if (pos < CAP) binned[(size_t)b * CAP + pos] = wc[k];
    }
}

// ---- per bucket: degree, dinv, rowbeg/rowend, in-place sort, xs16 ----------

__global__ void k_reorder(const int* __restrict__ cursor, unsigned* __restrict__ binned,
                          const float* __restrict__ x, float* __restrict__ dinv,
                          int* __restrict__ rowbeg, int* __restrict__ rowend,
                          uint4* __restrict__ xs16, int N, int CAP) {
    __shared__ int hist[BN];
    __shared__ int offs[BN];
    __shared__ int curs[BN];
    __shared__ float sdv[BN];
    int t = threadIdx.x, b = blockIdx.x;
    int cnt = min(cursor[b], CAP);
    int gbase = b * CAP;
    unsigned ent[16];                    // ceil(CAP/TPB) <= 11
    int ne = 0;
    if (t < BN) hist[t] = 0;
    __syncthreads();
    for (int i = t; i < cnt; i += TPB) { // read ALL entries before any write
        unsigned w = binned[gbase + i];
        ent[ne++] = w;
        atomicAdd(&hist[w >> 17], 1);
    }
    __syncthreads();
    if (t < BN) offs[t] = hist[t];
    __syncthreads();
    for (int off = 1; off < BN; off <<= 1) {   // inclusive scan
        int v = 0;
        if (t >= off && t < BN) v = offs[t - off];
        __syncthreads();
        if (t < BN) offs[t] += v;
        __syncthreads();
    }
    if (t < BN) {
        int excl = offs[t] - hist[t];
        curs[t] = excl;
        float dv = rsqrtf((float)hist[t] + 1.0f);
        sdv[t] = dv;
        int v = (b << BSH) + t;
        if (v < N) {
            dinv[v] = dv;
            rowbeg[v] = gbase + excl;
            rowend[v] = gbase + excl + hist[t];
        }
    }
    __syncthreads();
    if (t < BN) {                        // xs16[v] = half8(x[v] * dinv[v])
        int vv = (b << BSH) + t;
        if (vv < N) {
            float4 a0 = ((const float4*)x)[(size_t)vv * 2];
            float4 a1 = ((const float4*)x)[(size_t)vv * 2 + 1];
            float d = sdv[t];
            __half2 h0 = __floats2half2_rn(a0.x * d, a0.y * d);
            __half2 h1 = __floats2half2_rn(a0.z * d, a0.w * d);
            __half2 h2 = __floats2half2_rn(a1.x * d, a1.y * d);
            __half2 h3 = __floats2half2_rn(a1.z * d, a1.w * d);
            uint4 u;
            u.x = *(unsigned*)&h0; u.y = *(unsigned*)&h1;
            u.z = *(unsigned*)&h2; u.w = *(unsigned*)&h3;
            xs16[vv] = u;
        }
    }
    for (int k = 0; k < ne; ++k) {       // write back node-sorted (src only)
        unsigned w = ent[k];
        int pos = atomicAdd(&curs[w >> 17], 1);
        binned[gbase + pos] = w & 0x1FFFF;
    }
}

// ---- layer-1 aggregation (8-dim): agg8 = (Σ xs[u] + xs[v])*dinv[v] ---------
// 4 lanes/node, quarter edge ranges, shfl_xor(1)+(2) combine.

__global__ void k_gather8(const uint4* __restrict__ xs16, const unsigned* __restrict__ adj,
                          const int* __restrict__ rowbeg, const int* __restrict__ rowend,
                          const float* __restrict__ dinv, float* __restrict__ agg8, int N) {
    int t = blockIdx.x * blockDim.x + threadIdx.x;
    if (t >= N * 4) return;
    int v = t >> 2, l = t & 3;
    int beg = rowbeg[v], end = rowend[v], len = end - beg;
    int b0 = beg + ((len * l) >> 2);
    int e0 = beg + ((len * (l + 1)) >> 2);
    float a[8] = {0, 0, 0, 0, 0, 0, 0, 0};
    for (int j = b0; j < e0; ++j) acc8(a, xs16[adj[j]]);
    if (l == 0) acc8(a, xs16[v]);                  // self loop
#pragma unroll
    for (int k = 0; k < 8; ++k) {
        a[k] += __shfl_xor(a[k], 1);
        a[k] += __shfl_xor(a[k], 2);
    }
    if (l == 0) {
        float d = dinv[v];
        ((float4*)agg8)[(size_t)v * 2] =
            make_float4(a[0] * d, a[1] * d, a[2] * d, a[3] * d);
        ((float4*)agg8)[(size_t)v * 2 + 1] =
            make_float4(a[4] * d, a[5] * d, a[6] * d, a[7] * d);
    }
}

// ---- fused dense: B16 = half( relu(agg8@W1+b1)@W2 * dinv ) -----------------

__global__ void k_l12(const float* __restrict__ agg8, const float* __restrict__ W1,
                      const float* __restrict__ b1, const float* __restrict__ W2,
                      const float* __restrict__ dinv, unsigned* __restrict__ B16, int N) {
    __shared__ float sW1[8 * 32];
    __shared__ float sW2[32 * 32];
    __shared__ float sA[8 * 8];
    __shared__ float sH[8 * 32];
    int t = threadIdx.x;
    sW1[t] = W1[t];
#pragma unroll
    for (int i = t; i < 1024; i += TPB) sW2[i] = W2[i];
    int v0 = blockIdx.x * 8;
    if (t < 64) {
        int vv = v0 + (t >> 3);
        sA[t] = (vv < N) ? agg8[(size_t)v0 * 8 + t] : 0.f;
    }
    __syncthreads();
    int dl = t >> 5, f = t & 31;
    int v = v0 + dl;
    float s = b1[f];
#pragma unroll
    for (int k = 0; k < 8; ++k) s = fmaf(sA[dl * 8 + k], sW1[k * 32 + f], s);
    sH[dl * 32 + f] = fmaxf(s, 0.f);
    __syncthreads();
    if (v >= N) return;
    float s2 = 0.f;
#pragma unroll
    for (int k = 0; k < 32; ++k) s2 = fmaf(sH[dl * 32 + k], sW2[k * 32 + f], s2);
    s2 *= dinv[v];
    float partner = __shfl_xor(s2, 1);
    if ((f & 1) == 0) {
        __half2 h = __floats2half2_rn(s2, partner);
        B16[(size_t)v * 16 + (f >> 1)] = *(unsigned*)&h;
    }
}

// ---- layer-2 gather + per-block partial max pool ---------------------------
// 16 lanes/node: chunk q=sub&3 (16 B of the 64 B row), quarter qq=sub>>2.
// shfl_xor(4)+(8) combine; partial max init 0 == relu floor; block writes its
// 32-float partial row (no global atomics).

__global__ void k_gather32(const uint4* __restrict__ B16, const unsigned* __restrict__ adj,
                           const int* __restrict__ rowbeg, const int* __restrict__ rowend,
                           const float* __restrict__ dinv, const float* __restrict__ b2,
                           float* __restrict__ partial, int N) {
    int tid = threadIdx.x;
    int sub = tid & 15, q = sub & 3, qq = sub >> 2;
    float bb[8];
#pragma unroll
    for (int k = 0; k < 8; ++k) bb[k] = b2[q * 8 + k];
    float m[8] = {0, 0, 0, 0, 0, 0, 0, 0};
    int gstride = (gridDim.x * blockDim.x) >> 4;
    for (int v = (blockIdx.x * blockDim.x + tid) >> 4; v < N; v += gstride) {
        int beg = rowbeg[v], end = rowend[v], len = end - beg;
        int b0 = beg + ((len * qq) >> 2);
        int e0 = beg + ((len * (qq + 1)) >> 2);
        float a[8] = {0, 0, 0, 0, 0, 0, 0, 0};
        int j = b0;
        for (; j + 2 <= e0; j += 2) {
            int s0 = adj[j], s1 = adj[j + 1];
            uint4 u0 = B16[(size_t)s0 * 4 + q];
            uint4 u1 = B16[(size_t)s1 * 4 + q];
            acc8(a, u0); acc8(a, u1);
        }
        for (; j < e0; ++j) acc8(a, B16[(size_t)adj[j] * 4 + q]);
        if (qq == 0) acc8(a, B16[(size_t)v * 4 + q]);   // self loop
#pragma unroll
        for (int k = 0; k < 8; ++k) {
            a[k] += __shfl_xor(a[k], 4);
            a[k] += __shfl_xor(a[k], 8);
        }
        float d = dinv[v];
#pragma unroll
        for (int k = 0; k < 8; ++k) m[k] = fmaxf(m[k], fmaf(d, a[k], bb[k]));
    }
    __shared__ float red[TPB][8];
#pragma unroll
    for (int k = 0; k < 8; ++k) red[tid][k] = m[k];
    __syncthreads();
    for (int off = 128; off >= 16; off >>= 1) {   // stride keeps sub class
        if (tid < off) {
#pragma unroll
            for (int k = 0; k < 8; ++k)
                red[tid][k] = fmaxf(red[tid][k], red[tid + off][k]);
        }
        __syncthreads();
    }
    if (tid < 4) {                                 // fold the 4 quarters
        float r[8];
#pragma unroll
        for (int k = 0; k < 8; ++k)
            r[k] = fmaxf(fmaxf(red[tid][k], red[tid + 4][k]),
                         fmaxf(red[tid + 8][k], red[tid + 12][k]));
        float* p = partial + (size_t)blockIdx.x * 32 + tid * 8;
        ((float4*)p)[0] = make_float4(r[0], r[1], r[2], r[3]);
        ((float4*)p)[1] = make_float4(r[4], r[5], r[6], r[7]);
    }
}

// ---- head: reduce partials, fc, log_softmax --------------------------------

__global__ void k_head(const float* __restrict__ partial, int npart,
                       const float* __restrict__ fcW, const float* __restrict__ fcb,
                       float* __restrict__ out) {
    __shared__ float red[TPB];
    int t = threadIdx.x;
    int f = t & 31, r0 = t >> 5;
    float m = 0.f;
    for (int r = r0; r < npart; r += 8) m = fmaxf(m, partial[(size_t)r * 32 + f]);
    red[t] = m;
    __syncthreads();
    for (int off = 128; off >= 32; off >>= 1) {
        if (t < off) red[t] = fmaxf(red[t], red[t + off]);
        __syncthreads();
    }
    if (t != 0) return;
    float logit[5];
    float mx = -1e30f;
#pragma unroll
    for (int c = 0; c < 5; ++c) {
        float s = fcb[c];
#pragma unroll
        for (int ff = 0; ff < 32; ++ff) s += red[ff] * fcW[ff * 5 + c];
        logit[c] = s;
        mx = fmaxf(mx, s);
    }
    float lse = 0.f;
#pragma unroll
    for (int c = 0; c < 5; ++c) lse += expf(logit[c] - mx);
    lse = logf(lse) + mx;
#pragma unroll
    for (int c = 0; c < 5; ++c) out[c] = logit[c] - lse;
}

static inline size_t align256(size_t x) { return (x + 255) & ~size_t(255); }

extern "C" void kernel_launch(void* const* d_in, const int* in_sizes, int n_in,
                              void* d_out, int out_size, void* d_ws, size_t ws_size,
                              hipStream_t stream) {
    const float* x   = (const float*)d_in[0];
    const int*   ei  = (const int*)d_in[1];
    const float* W1  = (const float*)d_in[2];
    const float* b1  = (const float*)d_in[3];
    const float* W2  = (const float*)d_in[4];
    const float* b2  = (const float*)d_in[5];
    const float* fcW = (const float*)d_in[6];
    const float* fcb = (const float*)d_in[7];
    float* out = (float*)d_out;

    const int N = in_sizes[0] / 8;
    const int E = in_sizes[1] / 2;
    const int* src = ei;
    const int* dst = ei + E;

    const int NBK = (N + BN - 1) >> BSH;                  // 782 for N=100000
    const int avg = (E + NBK - 1) / NBK;                  // ~2047
    const int CAP = ((avg + (avg >> 2) + 64) + 15) & ~15; // mean +25% +slack

    char* ws = (char*)d_ws;
    size_t off = 0;
    int*      cursor  = (int*)(ws + off);      off += align256((size_t)NBK * 4);
    float*    dinv    = (float*)(ws + off);    off += align256((size_t)N * 4);
    int*      rowbeg  = (int*)(ws + off);      off += align256((size_t)N * 4);
    int*      rowend  = (int*)(ws + off);      off += align256((size_t)N * 4);
    uint4*    xs16    = (uint4*)(ws + off);    off += align256((size_t)N * 16);
    float*    agg8    = (float*)(ws + off);    off += align256((size_t)N * 8 * 4);
    unsigned* B16     = (unsigned*)(ws + off); off += align256((size_t)N * 64);
    float*    partial = (float*)(ws + off);    off += align256((size_t)G2_BLOCKS * 32 * 4);
    unsigned* binned  = (unsigned*)(ws + off);

    dim3 blk(TPB);

    hipMemsetAsync(cursor, 0, (size_t)NBK * 4, stream);

    k_bin<<<dim3((E + BIN_CHUNK - 1) / BIN_CHUNK), dim3(TPB_BIN), 0, stream>>>(
        src, dst, cursor, binned, E, NBK, CAP);
    k_reorder<<<dim3(NBK), blk, 0, stream>>>(cursor, binned, x, dinv, rowbeg, rowend,
                                             xs16, N, CAP);
    k_gather8<<<dim3((N * 4 + TPB - 1) / TPB), blk, 0, stream>>>(
        xs16, binned, rowbeg, rowend, dinv, agg8, N);
    k_l12<<<dim3((N + 7) / 8), blk, 0, stream>>>(agg8, W1, b1, W2, dinv, B16, N);
    k_gather32<<<dim3(G2_BLOCKS), blk, 0, stream>>>((const uint4*)B16, binned, rowbeg,
                                                    rowend, dinv, b2, partial, N);
    k_head<<<dim3(1), blk, 0, stream>>>(partial, G2_BLOCKS, fcW, fcb, out);
}